// Round 19
// baseline (186.181 us; speedup 1.0000x reference)
//
#include <hip/hip_runtime.h>
#include <hip/hip_fp16.h>
#include <math.h>

#define BN_EPS 1e-5f

typedef _Float16 f16x8 __attribute__((ext_vector_type(8)));
typedef float    f32x4 __attribute__((ext_vector_type(4)));

__device__ __forceinline__ float max3f(float a, float b, float c) {
    return fmaxf(fmaxf(a, b), c);
}

// ============================ K1: gates =================================
// One block per plane, 512 threads = 8 waves. A: streaming blurpool(maxpool).
// B: Toeplitz MFMA + BN + sigmoid -> gate (fp16) -> global workspace.
__global__ __launch_bounds__(512, 8)
void mra_gates(const float* __restrict__ x,
               const float* __restrict__ wh1,
               const float* __restrict__ wv1,
               const float* __restrict__ wh2,
               const float* __restrict__ wv2,
               const float* __restrict__ bng,
               const float* __restrict__ bnb,
               const float* __restrict__ bnm,
               const float* __restrict__ bnv,
               uint32_t* __restrict__ gws)      // gate ws: 2048 uints per plane
{
    __shared__ __align__(16) __half sxp_h[76][88];   // x_tem, zero halo, 16B rows
    __shared__ __align__(16) __half gate_d[64][64];  // dense gate, 8 KB
    __shared__ __align__(16) __half Tpad[13][48];    // Toeplitz taps, zero-padded

    const int plane = blockIdx.x;
    const int c     = plane & 255;
    const int tid   = threadIdx.x;
    const int lane  = tid & 63;
    const int w     = tid >> 6;
    const float* __restrict__ xp = x + (size_t)plane * 36864;

    // zero x_tem plane
    {
        int* z = (int*)&sxp_h[0][0];
        const int nInt = (76 * 88 * 2) / 4;   // 3344
        #pragma unroll
        for (int i = 0; i < 7; ++i) {
            const int idx = tid + (i << 9);
            if (idx < nInt) z[idx] = 0;
        }
    }
    // Toeplitz tap table T_e[d] = h1(e,d) + h2(e,d+e) + w1(e,d) + w2(d+e,d)
    {
        const float* __restrict__ wh1p = wh1 + c * 33;
        const float* __restrict__ wv1p = wv1 + c * 33;
        const float* __restrict__ wh2p = wh2 + c * 33;
        const float* __restrict__ wv2p = wv2 + c * 33;
        for (int s = tid; s < 13 * 48; s += 512) {
            const int er = s / 48;
            const int e  = er - 6;
            const int d  = (s - er * 48) - 24;
            float t = 0.f;
            if (e >= -5 && e <= 5 && d >= -1 && d <= 1)
                t += wh1p[(e + 5) * 3 + d + 1];
            if (e >= -5 && e <= 5 && d + e >= -1 && d + e <= 1)
                t += wh2p[(e + 5) * 3 + d + e + 1];
            if (e >= -1 && e <= 1 && d >= -5 && d <= 5)
                t += wv1p[(e + 1) * 11 + d + 5];
            if (d + e >= -1 && d + e <= 1 && d >= -5 && d <= 5)
                t += wv2p[(d + e + 1) * 11 + d + 5];
            Tpad[er][s - er * 48] = __float2half(t);
        }
    }
    __syncthreads();

    // Phase A: streaming maxpool3x3(SAME) + blur4x4 stride-3 -> 64x64
    {
        const int P0  = w << 3;
        const int r0  = 3 * P0 - 2;
        const int col = 3 * lane;

        float c0r[4], c1r[4], c2r[4];
        auto issue = [&](int k, int s) {
            int r = r0 + k;
            r = r < 0 ? 0 : (r > 191 ? 191 : r);   // clamp == maxpool SAME
            const float* rp = xp + r * 192 + col;
            c0r[s] = rp[0]; c1r[s] = rp[1]; c2r[s] = rp[2];
        };
        issue(0, 0); issue(1, 1); issue(2, 2); issue(3, 3);

        float h[3][4];
        float hb[3];
        float hbp = 0.f;

        #pragma unroll
        for (int k = 0; k < 27; ++k) {
            const int s = k & 3;
            const float cc0 = c0r[s], cc1 = c1r[s], cc2 = c2r[s];
            if (k + 4 < 27) issue(k + 4, s);

            float xm2 = __shfl_up(cc1, 1);
            float xm1 = __shfl_up(cc2, 1);
            float xp3 = __shfl_down(cc0, 1);
            if (lane == 0)  xm1 = cc0;
            if (lane == 63) xp3 = cc2;

            const float hm_m1 = max3f(xm2, xm1, cc0);
            const float hm_0  = max3f(xm1, cc0, cc1);
            const float hm_1  = max3f(cc0, cc1, cc2);
            const float hm_2  = max3f(cc1, cc2, xp3);

            float* hk = h[k % 3];
            hk[0] = (lane == 0) ? hm_1 : hm_m1;  // reflect: center -1 == center 1
            hk[1] = hm_0; hk[2] = hm_1; hk[3] = hm_2;

            if (k >= 2) {
                const float* a = h[(k - 2) % 3];
                const float* b = h[(k - 1) % 3];
                const float* d = h[k % 3];
                const float e4 =
                      0.125f * max3f(a[0], b[0], d[0])
                    + 0.375f * max3f(a[1], b[1], d[1])
                    + 0.375f * max3f(a[2], b[2], d[2])
                    + 0.125f * max3f(a[3], b[3], d[3]);
                if (k == 2) {
                    hbp = e4;
                } else {
                    hb[k % 3] = e4;
                    if (k % 3 == 2) {
                        const int i = (k - 5) / 3;
                        float a_out;
                        if (i == 0 && w == 0)
                            a_out = 0.375f * hb[0] + 0.5f * hb[1] + 0.125f * hb[2];
                        else
                            a_out = 0.125f * hbp + 0.375f * hb[0]
                                  + 0.375f * hb[1] + 0.125f * hb[2];
                        hbp = hb[2];
                        sxp_h[(w << 3) + i + 6][lane + 8] = __float2half(a_out);
                    }
                }
            }
        }
    }
    __syncthreads();

    // Phase B: Toeplitz MFMA (wave w owns 16x16 tiles 2w, 2w+1)
    {
        const int lr = lane & 15;
        const int lg = lane >> 4;
        const int t0 = 2 * w;
        const int P0  = (t0 >> 2) << 4;
        const int Q0a = (t0 & 3) << 4;
        const int Q0b = ((t0 + 1) & 3) << 4;
        const int tb  = lg * 8 + 16 - lr;

        f32x4 acc0 = {0.f, 0.f, 0.f, 0.f};
        f32x4 acc1 = {0.f, 0.f, 0.f, 0.f};

        #pragma unroll
        for (int e = -6; e <= 6; ++e) {
            const __half* trow = &Tpad[e + 6][0];
            f16x8 bf;
            #pragma unroll
            for (int j = 0; j < 8; ++j)
                bf[j] = *(const _Float16*)&trow[tb + j];
            const int row = P0 + lr + e + 6;
            const f16x8 a0 = *(const f16x8*)&sxp_h[row][Q0a + lg * 8];
            const f16x8 a1 = *(const f16x8*)&sxp_h[row][Q0b + lg * 8];
            acc0 = __builtin_amdgcn_mfma_f32_16x16x32_f16(a0, bf, acc0, 0, 0, 0);
            acc1 = __builtin_amdgcn_mfma_f32_16x16x32_f16(a1, bf, acc1, 0, 0, 0);
        }

        const float inv = bng[c] * rsqrtf(bnv[c] + BN_EPS);
        const float mu  = bnm[c];
        const float bt  = bnb[c];
        #pragma unroll
        for (int r = 0; r < 4; ++r) {
            const int gr = P0 + lg * 4 + r;
            const float g0 = 1.0f / (1.0f + __expf(-((acc0[r] - mu) * inv + bt)));
            const float g1 = 1.0f / (1.0f + __expf(-((acc1[r] - mu) * inv + bt)));
            gate_d[gr][Q0a + lr] = __float2half(g0);
            gate_d[gr][Q0b + lr] = __float2half(g1);
        }
    }
    __syncthreads();

    // gate -> global ws (coalesced uint copy)
    {
        const uint32_t* gu = (const uint32_t*)&gate_d[0][0];
        uint32_t* gp = gws + (size_t)plane * 2048;
        #pragma unroll
        for (int i = 0; i < 4; ++i) gp[tid + (i << 9)] = gu[tid + (i << 9)];
    }
}

// ============================ K2: apply =================================
// One block per plane, REVERSE order (L3 retention: K1's last-read planes are
// L3-hot at K2 start). 256 threads: gate->LDS, then out = x * gate[i/3][j/3].
__global__ __launch_bounds__(256, 8)
void mra_apply(const float* __restrict__ x,
               const uint32_t* __restrict__ gws,
               float* __restrict__ out)
{
    __shared__ __align__(16) __half gate_l[64][64];   // 8 KB

    const int plane = 2047 - blockIdx.x;               // reverse
    const int tid   = threadIdx.x;
    const float* __restrict__ xp = x   + (size_t)plane * 36864;
    float* __restrict__       op = out + (size_t)plane * 36864;

    {
        uint32_t* gl = (uint32_t*)&gate_l[0][0];
        const uint32_t* gp = gws + (size_t)plane * 2048;
        #pragma unroll
        for (int i = 0; i < 8; ++i) gl[tid + (i << 8)] = gp[tid + (i << 8)];
    }
    __syncthreads();

    const float4* __restrict__ x4 = (const float4*)xp;
    float4* __restrict__       o4 = (float4*)op;
    int rowj[3], gcj[3], rrj[3];
    #pragma unroll
    for (int j = 0; j < 3; ++j) {
        const int idx0 = tid + (j << 8);
        const int rw   = idx0 / 48;            // 48 float4 per row
        const int c4   = idx0 - rw * 48;
        rowj[j] = rw;
        const int jb = c4 << 2;
        gcj[j] = jb / 3;
        rrj[j] = jb - 3 * gcj[j];
    }
    #pragma unroll
    for (int m = 0; m < 12; ++m) {
        #pragma unroll
        for (int j = 0; j < 3; ++j) {
            const int row = rowj[j] + (m << 4);
            const int idx = tid + ((m * 3 + j) << 8);
            const int gr  = row / 3;
            const float g0 = __half2float(gate_l[gr][gcj[j]]);
            const float g1 = __half2float(gate_l[gr][gcj[j] + 1]);
            const float4 xv = x4[idx];
            float4 ov;
            const float s1 = (rrj[j] == 2) ? g1 : g0;
            const float s2 = (rrj[j] >= 1) ? g1 : g0;
            ov.x = xv.x * g0;
            ov.y = xv.y * s1;
            ov.z = xv.z * s2;
            ov.w = xv.w * g1;
            o4[idx] = ov;
        }
    }
}

// ===================== fallback: fused (round-18) =======================
__global__ __launch_bounds__(512, 8)
void mra_fused(const float* __restrict__ x,
               const float* __restrict__ wh1,
               const float* __restrict__ wv1,
               const float* __restrict__ wh2,
               const float* __restrict__ wv2,
               const float* __restrict__ bng,
               const float* __restrict__ bnb,
               const float* __restrict__ bnm,
               const float* __restrict__ bnv,
               float* __restrict__ out)
{
    __shared__ __align__(16) __half sxp_h[76][88];
    __shared__ __align__(16) __half gate_h[64][72];
    __shared__ __align__(16) __half Tpad[13][48];

    const int plane = blockIdx.x;
    const int c     = plane & 255;
    const int tid   = threadIdx.x;
    const int lane  = tid & 63;
    const int w     = tid >> 6;
    const float* __restrict__ xp = x   + (size_t)plane * 36864;
    float* __restrict__       op = out + (size_t)plane * 36864;

    {
        int* z = (int*)&sxp_h[0][0];
        const int nInt = (76 * 88 * 2) / 4;
        #pragma unroll
        for (int i = 0; i < 7; ++i) {
            const int idx = tid + (i << 9);
            if (idx < nInt) z[idx] = 0;
        }
    }
    {
        const float* __restrict__ wh1p = wh1 + c * 33;
        const float* __restrict__ wv1p = wv1 + c * 33;
        const float* __restrict__ wh2p = wh2 + c * 33;
        const float* __restrict__ wv2p = wv2 + c * 33;
        for (int s = tid; s < 13 * 48; s += 512) {
            const int er = s / 48;
            const int e  = er - 6;
            const int d  = (s - er * 48) - 24;
            float t = 0.f;
            if (e >= -5 && e <= 5 && d >= -1 && d <= 1)
                t += wh1p[(e + 5) * 3 + d + 1];
            if (e >= -5 && e <= 5 && d + e >= -1 && d + e <= 1)
                t += wh2p[(e + 5) * 3 + d + e + 1];
            if (e >= -1 && e <= 1 && d >= -5 && d <= 5)
                t += wv1p[(e + 1) * 11 + d + 5];
            if (d + e >= -1 && d + e <= 1 && d >= -5 && d <= 5)
                t += wv2p[(d + e + 1) * 11 + d + 5];
            Tpad[er][s - er * 48] = __float2half(t);
        }
    }
    __syncthreads();

    {
        const int P0  = w << 3;
        const int r0  = 3 * P0 - 2;
        const int col = 3 * lane;

        float c0r[4], c1r[4], c2r[4];
        auto issue = [&](int k, int s) {
            int r = r0 + k;
            r = r < 0 ? 0 : (r > 191 ? 191 : r);
            const float* rp = xp + r * 192 + col;
            c0r[s] = rp[0]; c1r[s] = rp[1]; c2r[s] = rp[2];
        };
        issue(0, 0); issue(1, 1); issue(2, 2); issue(3, 3);

        float h[3][4];
        float hb[3];
        float hbp = 0.f;

        #pragma unroll
        for (int k = 0; k < 27; ++k) {
            const int s = k & 3;
            const float cc0 = c0r[s], cc1 = c1r[s], cc2 = c2r[s];
            if (k + 4 < 27) issue(k + 4, s);

            float xm2 = __shfl_up(cc1, 1);
            float xm1 = __shfl_up(cc2, 1);
            float xp3 = __shfl_down(cc0, 1);
            if (lane == 0)  xm1 = cc0;
            if (lane == 63) xp3 = cc2;

            const float hm_m1 = max3f(xm2, xm1, cc0);
            const float hm_0  = max3f(xm1, cc0, cc1);
            const float hm_1  = max3f(cc0, cc1, cc2);
            const float hm_2  = max3f(cc1, cc2, xp3);

            float* hk = h[k % 3];
            hk[0] = (lane == 0) ? hm_1 : hm_m1;
            hk[1] = hm_0; hk[2] = hm_1; hk[3] = hm_2;

            if (k >= 2) {
                const float* a = h[(k - 2) % 3];
                const float* b = h[(k - 1) % 3];
                const float* d = h[k % 3];
                const float e4 =
                      0.125f * max3f(a[0], b[0], d[0])
                    + 0.375f * max3f(a[1], b[1], d[1])
                    + 0.375f * max3f(a[2], b[2], d[2])
                    + 0.125f * max3f(a[3], b[3], d[3]);
                if (k == 2) {
                    hbp = e4;
                } else {
                    hb[k % 3] = e4;
                    if (k % 3 == 2) {
                        const int i = (k - 5) / 3;
                        float a_out;
                        if (i == 0 && w == 0)
                            a_out = 0.375f * hb[0] + 0.5f * hb[1] + 0.125f * hb[2];
                        else
                            a_out = 0.125f * hbp + 0.375f * hb[0]
                                  + 0.375f * hb[1] + 0.125f * hb[2];
                        hbp = hb[2];
                        sxp_h[(w << 3) + i + 6][lane + 8] = __float2half(a_out);
                    }
                }
            }
        }
    }
    __syncthreads();

    {
        const int lr = lane & 15;
        const int lg = lane >> 4;
        const int t0 = 2 * w;
        const int P0  = (t0 >> 2) << 4;
        const int Q0a = (t0 & 3) << 4;
        const int Q0b = ((t0 + 1) & 3) << 4;
        const int tb  = lg * 8 + 16 - lr;

        f32x4 acc0 = {0.f, 0.f, 0.f, 0.f};
        f32x4 acc1 = {0.f, 0.f, 0.f, 0.f};

        #pragma unroll
        for (int e = -6; e <= 6; ++e) {
            const __half* trow = &Tpad[e + 6][0];
            f16x8 bf;
            #pragma unroll
            for (int j = 0; j < 8; ++j)
                bf[j] = *(const _Float16*)&trow[tb + j];
            const int row = P0 + lr + e + 6;
            const f16x8 a0 = *(const f16x8*)&sxp_h[row][Q0a + lg * 8];
            const f16x8 a1 = *(const f16x8*)&sxp_h[row][Q0b + lg * 8];
            acc0 = __builtin_amdgcn_mfma_f32_16x16x32_f16(a0, bf, acc0, 0, 0, 0);
            acc1 = __builtin_amdgcn_mfma_f32_16x16x32_f16(a1, bf, acc1, 0, 0, 0);
        }

        const float inv = bng[c] * rsqrtf(bnv[c] + BN_EPS);
        const float mu  = bnm[c];
        const float bt  = bnb[c];
        #pragma unroll
        for (int r = 0; r < 4; ++r) {
            const int gr = P0 + lg * 4 + r;
            const float g0 = 1.0f / (1.0f + __expf(-((acc0[r] - mu) * inv + bt)));
            const float g1 = 1.0f / (1.0f + __expf(-((acc1[r] - mu) * inv + bt)));
            gate_h[gr][Q0a + lr] = __float2half(g0);
            gate_h[gr][Q0b + lr] = __float2half(g1);
        }
    }
    __syncthreads();

    const float4* __restrict__ x4 = (const float4*)xp + w * 1152;
    float4* __restrict__       o4 = (float4*)op       + w * 1152;
    int rlj[3], gcj[3], rrj[3];
    #pragma unroll
    for (int j = 0; j < 3; ++j) {
        const int idx0 = lane + (j << 6);
        const int rw   = idx0 / 48;
        const int c4   = idx0 - rw * 48;
        rlj[j] = rw;
        const int jb = c4 << 2;
        gcj[j] = jb / 3;
        rrj[j] = jb - 3 * gcj[j];
    }
    #pragma unroll
    for (int u = 0; u < 6; ++u) {
        #pragma unroll
        for (int j = 0; j < 3; ++j) {
            const int row_l = rlj[j] + (u << 2);
            const int idx   = lane + ((u * 3 + j) << 6);
            const int gr    = (w << 3) + row_l / 3;
            const float g0 = __half2float(gate_h[gr][gcj[j]]);
            const float g1 = __half2float(gate_h[gr][gcj[j] + 1]);
            const float4 xv = x4[idx];
            float4 ov;
            const float s1 = (rrj[j] == 2) ? g1 : g0;
            const float s2 = (rrj[j] >= 1) ? g1 : g0;
            ov.x = xv.x * g0;
            ov.y = xv.y * s1;
            ov.z = xv.z * s2;
            ov.w = xv.w * g1;
            o4[idx] = ov;
        }
    }
}

extern "C" void kernel_launch(void* const* d_in, const int* in_sizes, int n_in,
                              void* d_out, int out_size, void* d_ws, size_t ws_size,
                              hipStream_t stream) {
    const float* x   = (const float*)d_in[0];
    const float* wh1 = (const float*)d_in[1];
    const float* wv1 = (const float*)d_in[2];
    const float* wh2 = (const float*)d_in[3];
    const float* wv2 = (const float*)d_in[4];
    const float* g   = (const float*)d_in[5];
    const float* b   = (const float*)d_in[6];
    const float* m   = (const float*)d_in[7];
    const float* v   = (const float*)d_in[8];

    const size_t gate_bytes = (size_t)2048 * 2048 * 4;   // 16.8 MB
    if (ws_size >= gate_bytes) {
        uint32_t* gws = (uint32_t*)d_ws;
        mra_gates<<<dim3(2048), dim3(512), 0, stream>>>(
            x, wh1, wv1, wh2, wv2, g, b, m, v, gws);
        mra_apply<<<dim3(2048), dim3(256), 0, stream>>>(
            x, gws, (float*)d_out);
    } else {
        mra_fused<<<dim3(2048), dim3(512), 0, stream>>>(
            x, wh1, wv1, wh2, wv2, g, b, m, v, (float*)d_out);
    }
}

// Round 20
// 159.954 us; speedup vs baseline: 1.1640x; 1.1640x over previous
//
#include <hip/hip_runtime.h>
#include <hip/hip_fp16.h>
#include <math.h>

#define BN_EPS 1e-5f

typedef _Float16 f16x8 __attribute__((ext_vector_type(8)));
typedef float    f32x4 __attribute__((ext_vector_type(4)));

__device__ __forceinline__ float max3f(float a, float b, float c) {
    return fmaxf(fmaxf(a, b), c);
}

// One block per (b,c) plane. 512 threads = 8 waves. 4 blocks/CU (wave-capped).
// Phase A: streaming blurpool(maxpool3x3(x)) (r15).
// Phase B: Toeplitz MFMA (r18) — wave w owns gate rows 16(w>>1)..+15,
//          cols 32(w&1)..+31 (tiles 2w, 2w+1).
// Phase C: WAVE-LOCAL — wave w writes out rows 48(w>>1)..+47, cols 96(w&1)..+95,
//          which need exactly wave w's own gate region -> NO block barrier
//          after B (r18's post-B __syncthreads cost ~25us vs r15's drain).
__global__ __launch_bounds__(512, 8)
void mra_fused(const float* __restrict__ x,
               const float* __restrict__ wh1,
               const float* __restrict__ wv1,
               const float* __restrict__ wh2,
               const float* __restrict__ wv2,
               const float* __restrict__ bng,
               const float* __restrict__ bnb,
               const float* __restrict__ bnm,
               const float* __restrict__ bnv,
               float* __restrict__ out)
{
    __shared__ __align__(16) __half sxp_h[76][88];   // x_tem, zero halo, 16B rows
    __shared__ __align__(16) __half gate_h[64][72];  // gate
    __shared__ __align__(16) __half Tpad[13][48];    // Toeplitz taps, zero-padded

    const int plane = blockIdx.x;       // b*256 + c
    const int c     = plane & 255;
    const int tid   = threadIdx.x;
    const int lane  = tid & 63;
    const int w     = tid >> 6;         // 0..7
    const float* __restrict__ xp = x   + (size_t)plane * 36864;
    float* __restrict__       op = out + (size_t)plane * 36864;

    // ---- zero x_tem plane (halo + col pad must be 0) ----
    {
        int* z = (int*)&sxp_h[0][0];
        const int nInt = (76 * 88 * 2) / 4;   // 3344
        #pragma unroll
        for (int i = 0; i < 7; ++i) {
            const int idx = tid + (i << 9);
            if (idx < nInt) z[idx] = 0;
        }
    }
    // ---- Toeplitz tap table T_e[d] = h1(e,d)+h2(e,d+e)+w1(e,d)+w2(d+e,d) ----
    {
        const float* __restrict__ wh1p = wh1 + c * 33;
        const float* __restrict__ wv1p = wv1 + c * 33;
        const float* __restrict__ wh2p = wh2 + c * 33;
        const float* __restrict__ wv2p = wv2 + c * 33;
        for (int s = tid; s < 13 * 48; s += 512) {
            const int er = s / 48;
            const int e  = er - 6;
            const int d  = (s - er * 48) - 24;
            float t = 0.f;
            if (e >= -5 && e <= 5 && d >= -1 && d <= 1)
                t += wh1p[(e + 5) * 3 + d + 1];
            if (e >= -5 && e <= 5 && d + e >= -1 && d + e <= 1)
                t += wh2p[(e + 5) * 3 + d + e + 1];
            if (e >= -1 && e <= 1 && d >= -5 && d <= 5)
                t += wv1p[(e + 1) * 11 + d + 5];
            if (d + e >= -1 && d + e <= 1 && d >= -5 && d <= 5)
                t += wv2p[(d + e + 1) * 11 + d + 5];
            Tpad[er][s - er * 48] = __float2half(t);
        }
    }
    __syncthreads();

    // ---- Phase A: streaming maxpool3x3(SAME) + blur4x4 stride-3 -> 64x64 ----
    {
        const int P0  = w << 3;
        const int r0  = 3 * P0 - 2;
        const int col = 3 * lane;

        float c0r[4], c1r[4], c2r[4];
        auto issue = [&](int k, int s) {
            int r = r0 + k;
            r = r < 0 ? 0 : (r > 191 ? 191 : r);   // clamp == maxpool SAME
            const float* rp = xp + r * 192 + col;
            c0r[s] = rp[0]; c1r[s] = rp[1]; c2r[s] = rp[2];
        };
        issue(0, 0); issue(1, 1); issue(2, 2); issue(3, 3);

        float h[3][4];
        float hb[3];
        float hbp = 0.f;

        #pragma unroll
        for (int k = 0; k < 27; ++k) {
            const int s = k & 3;
            const float cc0 = c0r[s], cc1 = c1r[s], cc2 = c2r[s];
            if (k + 4 < 27) issue(k + 4, s);

            float xm2 = __shfl_up(cc1, 1);
            float xm1 = __shfl_up(cc2, 1);
            float xp3 = __shfl_down(cc0, 1);
            if (lane == 0)  xm1 = cc0;
            if (lane == 63) xp3 = cc2;

            const float hm_m1 = max3f(xm2, xm1, cc0);
            const float hm_0  = max3f(xm1, cc0, cc1);
            const float hm_1  = max3f(cc0, cc1, cc2);
            const float hm_2  = max3f(cc1, cc2, xp3);

            float* hk = h[k % 3];
            hk[0] = (lane == 0) ? hm_1 : hm_m1;  // reflect: center -1 == center 1
            hk[1] = hm_0; hk[2] = hm_1; hk[3] = hm_2;

            if (k >= 2) {
                const float* a = h[(k - 2) % 3];
                const float* b = h[(k - 1) % 3];
                const float* d = h[k % 3];
                const float e4 =
                      0.125f * max3f(a[0], b[0], d[0])
                    + 0.375f * max3f(a[1], b[1], d[1])
                    + 0.375f * max3f(a[2], b[2], d[2])
                    + 0.125f * max3f(a[3], b[3], d[3]);
                if (k == 2) {
                    hbp = e4;
                } else {
                    hb[k % 3] = e4;
                    if (k % 3 == 2) {
                        const int i = (k - 5) / 3;
                        float a_out;
                        if (i == 0 && w == 0)
                            a_out = 0.375f * hb[0] + 0.5f * hb[1] + 0.125f * hb[2];
                        else
                            a_out = 0.125f * hbp + 0.375f * hb[0]
                                  + 0.375f * hb[1] + 0.125f * hb[2];
                        hbp = hb[2];
                        sxp_h[(w << 3) + i + 6][lane + 8] = __float2half(a_out);
                    }
                }
            }
        }
    }
    __syncthreads();   // A -> B (B reads cross-wave x_tem rows)

    const int s_  = w >> 1;             // row stripe 0..3
    const int hc  = w & 1;              // col half 0..1

    // ---- Phase B: Toeplitz MFMA. Wave w owns tiles 2w, 2w+1 ----
    {
        const int lr = lane & 15;
        const int lg = lane >> 4;
        const int P0  = s_ << 4;               // gate rows 16s..16s+15
        const int Q0a = (hc << 5);             // cols 32hc..
        const int Q0b = Q0a + 16;
        const int tb  = lg * 8 + 16 - lr;      // Tpad idx base (d+24 for j=0)

        f32x4 acc0 = {0.f, 0.f, 0.f, 0.f};
        f32x4 acc1 = {0.f, 0.f, 0.f, 0.f};

        #pragma unroll
        for (int e = -6; e <= 6; ++e) {
            const __half* trow = &Tpad[e + 6][0];
            f16x8 bf;
            #pragma unroll
            for (int j = 0; j < 8; ++j)
                bf[j] = *(const _Float16*)&trow[tb + j];
            const int row = P0 + lr + e + 6;
            const f16x8 a0 = *(const f16x8*)&sxp_h[row][Q0a + lg * 8];
            const f16x8 a1 = *(const f16x8*)&sxp_h[row][Q0b + lg * 8];
            acc0 = __builtin_amdgcn_mfma_f32_16x16x32_f16(a0, bf, acc0, 0, 0, 0);
            acc1 = __builtin_amdgcn_mfma_f32_16x16x32_f16(a1, bf, acc1, 0, 0, 0);
        }

        // BN + sigmoid -> gate (C/D layout: col=lane&15, row=(lane>>4)*4+r)
        const float inv = bng[c] * rsqrtf(bnv[c] + BN_EPS);
        const float mu  = bnm[c];
        const float bt  = bnb[c];
        #pragma unroll
        for (int r = 0; r < 4; ++r) {
            const int gr = P0 + lg * 4 + r;
            const float g0 = 1.0f / (1.0f + __expf(-((acc0[r] - mu) * inv + bt)));
            const float g1 = 1.0f / (1.0f + __expf(-((acc1[r] - mu) * inv + bt)));
            gate_h[gr][Q0a + lr] = __float2half(g0);
            gate_h[gr][Q0b + lr] = __float2half(g1);
        }
    }
    __builtin_amdgcn_wave_barrier();   // order own-wave BN ds_writes before C
                                       // ds_reads (gate region is wave-local)

    // ---- Phase C (wave-local): out rows 48s..48s+47, cols 96hc..96hc+95 ----
    {
        const float4* __restrict__ x4 = (const float4*)xp;
        float4* __restrict__       o4 = (float4*)op;
        const int R0 = 48 * s_;
        int rl0[3], f4c[3], gc0[3], rr0[3];
        #pragma unroll
        for (int j = 0; j < 3; ++j) {
            const int idx0 = lane + (j << 6);      // 0..191
            const int rl   = idx0 / 24;            // 0..7 (24 float4 per segment)
            const int k0   = idx0 - rl * 24;
            rl0[j] = rl;
            f4c[j] = 24 * hc + k0;
            const int jb = k0 << 2;                // 4*k0 (mod-96 part)
            gc0[j] = 32 * hc + jb / 3;
            rr0[j] = jb - 3 * (jb / 3);
        }
        #pragma unroll
        for (int u = 0; u < 6; ++u) {
            #pragma unroll
            for (int j = 0; j < 3; ++j) {
                const int row_l = rl0[j] + (u << 3);     // 0..47
                const int idx   = (R0 + row_l) * 48 + f4c[j];
                const int gr    = (s_ << 4) + row_l / 3; // gate row 16s..
                const float g0 = __half2float(gate_h[gr][gc0[j]]);
                const float g1 = __half2float(gate_h[gr][gc0[j] + 1]);
                const float4 xv = x4[idx];
                float4 ov;
                const float s1 = (rr0[j] == 2) ? g1 : g0;
                const float s2 = (rr0[j] >= 1) ? g1 : g0;
                ov.x = xv.x * g0;
                ov.y = xv.y * s1;
                ov.z = xv.z * s2;
                ov.w = xv.w * g1;
                o4[idx] = ov;
            }
        }
    }
}

extern "C" void kernel_launch(void* const* d_in, const int* in_sizes, int n_in,
                              void* d_out, int out_size, void* d_ws, size_t ws_size,
                              hipStream_t stream) {
    const float* x   = (const float*)d_in[0];
    const float* wh1 = (const float*)d_in[1];
    const float* wv1 = (const float*)d_in[2];
    const float* wh2 = (const float*)d_in[3];
    const float* wv2 = (const float*)d_in[4];
    const float* g   = (const float*)d_in[5];
    const float* b   = (const float*)d_in[6];
    const float* m   = (const float*)d_in[7];
    const float* v   = (const float*)d_in[8];

    mra_fused<<<dim3(2048), dim3(512), 0, stream>>>(
        x, wh1, wv1, wh2, wv2, g, b, m, v, (float*)d_out);
}